// Round 3
// baseline (288.715 us; speedup 1.0000x reference)
//
#include <hip/hip_runtime.h>
#include <math.h>

#define TPB 256
#define ROWS 4   // rows per block; grid 1024 -> exactly 4 blocks/CU, all co-resident

// Packed complex: clang ext_vector_type(2) float -> VOP3P v_pk_{add,mul,fma}_f32
typedef float cplx __attribute__((ext_vector_type(2)));

__device__ __forceinline__ cplx cmul(cplx a, cplx b) {
    // (a.x*b.x - a.y*b.y, a.x*b.y + a.y*b.x)
    return a.xx * b + cplx{-a.y, a.y} * b.yx;
}

__device__ __forceinline__ void dft4(cplx& a, cplx& b, cplx& c, cplx& d) {
    cplx t0 = a + c, t1 = a - c, t2 = b + d, t3 = b - d;
    a = t0 + t2;
    c = t0 - t2;
    cplx jt3 = cplx{t3.y, -t3.x};   // -i * t3
    b = t1 + jt3;
    d = t1 - jt3;
}

// In-register 16-point DFT. Input v[l]; output y[m] lands at v[T16(m)].
// T16 is an involution (4x4 transpose) -> twiddle in place, write from a[j].
#define T16(j) (4 * ((j) & 3) + ((j) >> 2))

__device__ __forceinline__ void dft16(cplx v[16]) {
#pragma unroll
    for (int j = 0; j < 4; ++j) dft4(v[j], v[4 + j], v[8 + j], v[12 + j]);
    const float C1 = 0.9238795325112867f, S1 = 0.3826834323650898f;
    const float R2 = 0.7071067811865476f;
    v[5]  = cmul(v[5],  cplx{ C1, -S1});   // w16^1
    v[9]  = cmul(v[9],  cplx{ R2, -R2});   // w16^2
    v[13] = cmul(v[13], cplx{ S1, -C1});   // w16^3
    v[6]  = cmul(v[6],  cplx{ R2, -R2});   // w16^2
    v[10] = cplx{v[10].y, -v[10].x};       // * w16^4 = -i
    v[14] = cmul(v[14], cplx{-R2, -R2});   // w16^6
    v[7]  = cmul(v[7],  cplx{ S1, -C1});   // w16^3
    v[11] = cmul(v[11], cplx{-R2, -R2});   // w16^6
    v[15] = cmul(v[15], cplx{-C1,  S1});   // w16^9
#pragma unroll
    for (int b = 0; b < 4; ++b) dft4(v[4 * b], v[4 * b + 1], v[4 * b + 2], v[4 * b + 3]);
}

// R2 post-mortem: VALU-issue cut 33->21.6us yet dur ROSE (79->86.5). All
// variants plateau at ~80us because each block's global traffic is one 32KB
// burst followed by ~25us of FFT with ZERO loads in flight -> HBM duty cycle
// ~10% (measured 0.78 TB/s == 256CU*2.5blk*32KB/27us). This round pipelines
// ROWS=4 rows/block with register prefetch: next row's 16 global_load_dwordx2
// issue before the FFT, counted vmcnt waits land at the a<-pf copy AFTER it.
__global__ __launch_bounds__(TPB, 4) void snr_kernel(const float* __restrict__ x,
                                                     const float* __restrict__ targets,
                                                     float* __restrict__ out) {
    __shared__ __align__(16) cplx Z[4096];   // 32768 B
    float* zf = (float*)Z;                   // overlay: caps [0..5], red [8..11]
                                             // (cplx Z[0..5] -- only t0 rewrites
                                             // these in next stage0, same-thread
                                             // ordered; no extra barrier needed)

    const int t = threadIdx.x;
    const int tl = t & 15;
    const int rb = t ^ ((t >> 4) & 15);   // phys base for logical slots t+256l
    const int wb0 = t << 4;
    const int row0 = blockIdx.x * ROWS;

    cplx a[16], pf[16];
    {
        const cplx* rowp = (const cplx*)(x + (size_t)row0 * 8192);
#pragma unroll
        for (int l = 0; l < 16; ++l) a[l] = rowp[t + 256 * l];
    }

    float lossSum = 0.f;

    for (int it = 0; it < ROWS; ++it) {
        // ---- prefetch next row: in flight across the whole FFT ----
        if (it + 1 < ROWS) {
            const cplx* rowp = (const cplx*)(x + (size_t)(row0 + it + 1) * 8192);
#pragma unroll
            for (int l = 0; l < 16; ++l) pf[l] = rowp[t + 256 * l];
        }

        // ---- every thread computes r (uniform) ----
        int r;
        {
            float tg = targets[row0 + it];
            const float df = 0.00244140625f;  // 10/4096 exact
            int c0 = (int)(tg * 409.6f) - 2;
            if (c0 < 0) c0 = 0;
            r = c0;
            float best = fabsf(df * (float)c0 - tg);
            for (int i = c0 + 1; i <= c0 + 4 && i <= 4096; ++i) {
                float dd = fabsf(df * (float)i - tg);
                if (dd < best) { best = dd; r = i; }  // strict <: argmin ties
            }
        }

        // ======== stage 0: s=1, n=4096; logical dest g = 16t + m ========
        dft16(a);
        {
            float ang = -1.5339807878856412e-3f * (float)t;  // -2pi/4096 * t
            float sn, cs; __sincosf(ang, &sn, &cs);
            cplx w1 = cplx{cs, sn};
            cplx w2 = cmul(w1, w1), w3 = cmul(w2, w1);
            cplx w4 = cmul(w2, w2), w8 = cmul(w4, w4), w12 = cmul(w8, w4);
            cplx wa[4] = {cplx{1.f, 0.f}, w1, w2, w3};
            cplx wb[4] = {cplx{1.f, 0.f}, w4, w8, w12};
#pragma unroll
            for (int m = 1; m < 16; ++m) {
                int j = T16(m);
                a[j] = cmul(a[j], cmul(wb[m >> 2], wa[m & 3]));
            }
        }
#pragma unroll
        for (int j = 0; j < 16; ++j) Z[wb0 + (T16(j) ^ tl)] = a[j];
        __syncthreads();

        // ======== stage 1: s=16, n=256 ========
#pragma unroll
        for (int l = 0; l < 16; ++l) a[l] = Z[rb + (l << 8)];
        __syncthreads();   // in-place exchange: all reads before any writes
        dft16(a);
        {
            const int p = t >> 4;
            float ang = -0.02454369260617026f * (float)p;  // -2pi/256 * p
            float sn, cs; __sincosf(ang, &sn, &cs);
            cplx w1 = cplx{cs, sn};
            cplx w2 = cmul(w1, w1), w3 = cmul(w2, w1);
            cplx w4 = cmul(w2, w2), w8 = cmul(w4, w4), w12 = cmul(w8, w4);
            cplx wa[4] = {cplx{1.f, 0.f}, w1, w2, w3};
            cplx wb[4] = {cplx{1.f, 0.f}, w4, w8, w12};
#pragma unroll
            for (int m = 1; m < 16; ++m) {
                int j = T16(m);
                a[j] = cmul(a[j], cmul(wb[m >> 2], wa[m & 3]));
            }
        }
        {
            const int base1 = (t >> 4) << 8;   // 256p
#pragma unroll
            for (int m = 0; m < 16; ++m) {
                Z[base1 + (m << 4) + (tl ^ m)] = a[T16(m)];
            }
        }
        __syncthreads();

        // ======== stage 2: s=256, p=0 (no twiddle) ========
#pragma unroll
        for (int l = 0; l < 16; ++l) a[l] = Z[rb + (l << 8)];
        __syncthreads();
        dft16(a);
        // a[T16(m)] = Z4096 bin (t + 256m)

        // ======== export full spectrum: bin b=t+256m -> logical 16t+m ========
#pragma unroll
        for (int j = 0; j < 16; ++j) Z[wb0 + (T16(j) ^ tl)] = a[j];
        __syncthreads();

        // ======== band sum: bins [273,1706] == {t+256m : m in [1,6]} ========
        float band = 0.f;
        {
            float ang = -7.669903939428206e-4f * (float)t;  // -pi/4096 * t
            float sn, cs; __sincosf(ang, &sn, &cs);
            cplx wku = cplx{cs, sn};
            const float WCc[7] = {1.f, 0.9807852804032304f, 0.9238795325112867f,
                                  0.8314696123025452f, 0.7071067811865476f,
                                  0.5555702330196022f, 0.3826834323650898f};
            const float WCs[7] = {0.f, -0.19509032201612825f, -0.3826834323650898f,
                                  -0.5555702330196022f, -0.7071067811865476f,
                                  -0.8314696123025452f, -0.9238795325112867f};
            const int pc = ((256 - t) & 255) << 4;
            const int pl = (16 - tl) & 15;
#pragma unroll
            for (int m = 1; m <= 6; ++m) {
                const int k = t + (m << 8);
                const int za = t ? (pc | ((15 - m) ^ pl)) : (16 - m);
                cplx Zk = a[T16(m)];
                cplx Zn = Z[za];
                cplx wk = cmul(wku, cplx{WCc[m], WCs[m]});
                cplx Znc = cplx{Zn.x, -Zn.y};
                cplx s  = Zk + Znc;
                cplx dd = Zk - Znc;
                cplx tt = cmul(wk, dd);
                cplx X  = s + cplx{tt.y, -tt.x};   // 2*X[k]
                float P = (X.x * X.x + X.y * X.y) * (1.0f / 32768.0f);
                if ((unsigned)(k - 273) <= 1433u) band += P;   // k in [273,1706]
            }
        }

        // ======== caps: threads 0..5 -> bins {r-1,r,r+1,2r-1,2r,2r+1} ========
        float capP = 0.f;
        if (t < 6) {
            const int c = (t < 3) ? (r - 1 + t) : (2 * r - 4 + t);
            const int kk = (c <= 2048) ? c : (4096 - c);
            const int nb = (4096 - kk) & 4095;
            const int zka = ((kk & 255) << 4) | ((kk >> 8) ^ (kk & 15));
            const int zna = ((nb & 255) << 4) | ((nb >> 8) ^ (nb & 15));
            cplx Zk = Z[zka], Zn = Z[zna];
            float ang = -7.669903939428206e-4f * (float)kk;  // -pi/4096 * kk
            float sn, cs; __sincosf(ang, &sn, &cs);
            cplx wk = cplx{cs, sn};
            cplx Znc = cplx{Zn.x, -Zn.y};
            cplx s  = Zk + Znc;
            cplx dd = Zk - Znc;
            cplx tt = cmul(wk, dd);
            cplx X  = (c <= 2048) ? (s + cplx{tt.y, -tt.x})    // 2*X[kk]
                                  : (s + cplx{-tt.y, tt.x});   // 2*conj(X[4096-kk])
            capP = (X.x * X.x + X.y * X.y) * (1.0f / 32768.0f);
        }
        __syncthreads();   // ALL Z reads (split + caps) done -> zf overlay safe

        if (t < 6) zf[t] = capP;

        // ---- block reduce band ----
#pragma unroll
        for (int off = 32; off > 0; off >>= 1) band += __shfl_down(band, off);
        if ((t & 63) == 0) zf[8 + (t >> 6)] = band;
        __syncthreads();

        if (t == 0) {
            float bb = zf[8] + zf[9] + zf[10] + zf[11];
            float S = zf[1] + zf[4] + 0.5f * (zf[0] + zf[2]);
            float noise = bb;
            const int r2 = 2 * r;
            if (r <= 1706)      noise -= zf[1];
            if (r - 1 >= 273)   noise -= 0.5f * zf[0];
            if (r + 1 <= 1706)  noise -= 0.5f * zf[2];
            if (r2 - 1 <= 1706) noise -= zf[3];
            if (r2 <= 1706)     noise -= zf[4];
            if (r2 + 1 <= 1706) noise -= zf[5];
            lossSum += -10.0f * log10f(S / (noise + 1.0f));
        }

        // ---- rotate pipeline: vmcnt wait for the prefetch lands HERE ----
        if (it + 1 < ROWS) {
#pragma unroll
            for (int l = 0; l < 16; ++l) a[l] = pf[l];
        }
    }

    if (t == 0) atomicAdd(out, lossSum * (1.0f / 4096.0f));
}

extern "C" void kernel_launch(void* const* d_in, const int* in_sizes, int n_in,
                              void* d_out, int out_size, void* d_ws, size_t ws_size,
                              hipStream_t stream) {
    const float* x = (const float*)d_in[0];    // outputs: (4096, 8192) fp32
    const float* tg = (const float*)d_in[1];   // targets: (4096, 1) fp32
    float* out = (float*)d_out;                // scalar fp32
    hipMemsetAsync(out, 0, sizeof(float), stream);
    snr_kernel<<<4096 / ROWS, TPB, 0, stream>>>(x, tg, out);
}

// Round 4
// 204.515 us; speedup vs baseline: 1.4117x; 1.4117x over previous
//
#include <hip/hip_runtime.h>
#include <math.h>

#define TPB 256
#define ROWS 4   // rows per block; grid 1024 -> 4 blocks/CU co-resident

// Packed complex: clang ext_vector_type(2) float -> VOP3P v_pk_{add,mul,fma}_f32
typedef float cplx __attribute__((ext_vector_type(2)));

__device__ __forceinline__ cplx cmul(cplx a, cplx b) {
    return a.xx * b + cplx{-a.y, a.y} * b.yx;
}

__device__ __forceinline__ void dft4(cplx& a, cplx& b, cplx& c, cplx& d) {
    cplx t0 = a + c, t1 = a - c, t2 = b + d, t3 = b - d;
    a = t0 + t2;
    c = t0 - t2;
    cplx jt3 = cplx{t3.y, -t3.x};   // -i * t3
    b = t1 + jt3;
    d = t1 - jt3;
}

// In-register 16-point DFT. Input v[l]; output y[m] lands at v[T16(m)].
// T16 is an involution (4x4 transpose) -> twiddle in place, write from v[j].
#define T16(j) (4 * ((j) & 3) + ((j) >> 2))

__device__ __forceinline__ void dft16(cplx v[16]) {
#pragma unroll
    for (int j = 0; j < 4; ++j) dft4(v[j], v[4 + j], v[8 + j], v[12 + j]);
    const float C1 = 0.9238795325112867f, S1 = 0.3826834323650898f;
    const float R2 = 0.7071067811865476f;
    v[5]  = cmul(v[5],  cplx{ C1, -S1});
    v[9]  = cmul(v[9],  cplx{ R2, -R2});
    v[13] = cmul(v[13], cplx{ S1, -C1});
    v[6]  = cmul(v[6],  cplx{ R2, -R2});
    v[10] = cplx{v[10].y, -v[10].x};
    v[14] = cmul(v[14], cplx{-R2, -R2});
    v[7]  = cmul(v[7],  cplx{ S1, -C1});
    v[11] = cmul(v[11], cplx{-R2, -R2});
    v[15] = cmul(v[15], cplx{-C1,  S1});
#pragma unroll
    for (int b = 0; b < 4; ++b) dft4(v[4 * b], v[4 * b + 1], v[4 * b + 2], v[4 * b + 3]);
}

// R3 post-mortem: pipelining mechanism confirmed (HBM flowed at 2.37 TB/s) but
// __launch_bounds__(256,4) capped VGPR at 64 while a[16]+pf[16] alone need 64
// -> ~450 B/thread scratch (WRITE_SIZE 117 MB), dur 157us. Fix: (256,2) lifts
// the cap to 256 (expect ~100-130 used, still 3-4 waves/SIMD; LDS allows 5
// blocks/CU), and the row loop is fully unrolled so a<-pf rotation is renamed
// away and the counted vmcnt wait lands at the next row's first butterfly.
__global__ __launch_bounds__(TPB, 2) void snr_kernel(const float* __restrict__ x,
                                                     const float* __restrict__ targets,
                                                     float* __restrict__ out) {
    __shared__ __align__(16) cplx Z[4096];   // 32768 B
    float* zf = (float*)Z;                   // overlay: caps [0..5], red [8..11]
                                             // (cplx Z[0..5] rewritten next
                                             // stage0 only by t0 = same thread
                                             // that read them; ordered)

    const int t = threadIdx.x;
    const int tl = t & 15;
    const int rb = t ^ ((t >> 4) & 15);   // phys base for logical slots t+256l
    const int wb0 = t << 4;
    const int row0 = blockIdx.x * ROWS;

    cplx a[16], pf[16];
    {
        const cplx* rowp = (const cplx*)(x + (size_t)row0 * 8192);
#pragma unroll
        for (int l = 0; l < 16; ++l) a[l] = rowp[t + 256 * l];
    }

    float lossSum = 0.f;

#pragma unroll
    for (int it = 0; it < ROWS; ++it) {
        // ---- prefetch next row: stays in flight across the whole FFT ----
        if (it + 1 < ROWS) {
            const cplx* rowp = (const cplx*)(x + (size_t)(row0 + it + 1) * 8192);
#pragma unroll
            for (int l = 0; l < 16; ++l) pf[l] = rowp[t + 256 * l];
        }

        // ---- every thread computes r (uniform) ----
        int r;
        {
            float tg = targets[row0 + it];
            const float df = 0.00244140625f;  // 10/4096 exact
            int c0 = (int)(tg * 409.6f) - 2;
            if (c0 < 0) c0 = 0;
            r = c0;
            float best = fabsf(df * (float)c0 - tg);
            for (int i = c0 + 1; i <= c0 + 4 && i <= 4096; ++i) {
                float dd = fabsf(df * (float)i - tg);
                if (dd < best) { best = dd; r = i; }  // strict <: argmin ties
            }
        }

        // ======== stage 0: s=1, n=4096; logical dest g = 16t + m ========
        dft16(a);
        {
            float ang = -1.5339807878856412e-3f * (float)t;  // -2pi/4096 * t
            float sn, cs; __sincosf(ang, &sn, &cs);
            cplx w1 = cplx{cs, sn};
            cplx w2 = cmul(w1, w1), w3 = cmul(w2, w1);
            cplx w4 = cmul(w2, w2), w8 = cmul(w4, w4), w12 = cmul(w8, w4);
            cplx wa[4] = {cplx{1.f, 0.f}, w1, w2, w3};
            cplx wb[4] = {cplx{1.f, 0.f}, w4, w8, w12};
#pragma unroll
            for (int m = 1; m < 16; ++m) {
                int j = T16(m);
                a[j] = cmul(a[j], cmul(wb[m >> 2], wa[m & 3]));
            }
        }
#pragma unroll
        for (int j = 0; j < 16; ++j) Z[wb0 + (T16(j) ^ tl)] = a[j];
        __syncthreads();

        // ======== stage 1: s=16, n=256 ========
#pragma unroll
        for (int l = 0; l < 16; ++l) a[l] = Z[rb + (l << 8)];
        __syncthreads();   // in-place exchange: all reads before any writes
        dft16(a);
        {
            const int p = t >> 4;
            float ang = -0.02454369260617026f * (float)p;  // -2pi/256 * p
            float sn, cs; __sincosf(ang, &sn, &cs);
            cplx w1 = cplx{cs, sn};
            cplx w2 = cmul(w1, w1), w3 = cmul(w2, w1);
            cplx w4 = cmul(w2, w2), w8 = cmul(w4, w4), w12 = cmul(w8, w4);
            cplx wa[4] = {cplx{1.f, 0.f}, w1, w2, w3};
            cplx wb[4] = {cplx{1.f, 0.f}, w4, w8, w12};
#pragma unroll
            for (int m = 1; m < 16; ++m) {
                int j = T16(m);
                a[j] = cmul(a[j], cmul(wb[m >> 2], wa[m & 3]));
            }
        }
        {
            const int base1 = (t >> 4) << 8;   // 256p
#pragma unroll
            for (int m = 0; m < 16; ++m) {
                Z[base1 + (m << 4) + (tl ^ m)] = a[T16(m)];
            }
        }
        __syncthreads();

        // ======== stage 2: s=256, p=0 (no twiddle) ========
#pragma unroll
        for (int l = 0; l < 16; ++l) a[l] = Z[rb + (l << 8)];
        __syncthreads();
        dft16(a);
        // a[T16(m)] = Z4096 bin (t + 256m)

        // ======== export full spectrum: bin b=t+256m -> logical 16t+m ========
#pragma unroll
        for (int j = 0; j < 16; ++j) Z[wb0 + (T16(j) ^ tl)] = a[j];
        __syncthreads();

        // ======== band sum: bins [273,1706] == {t+256m : m in [1,6]} ========
        float band = 0.f;
        {
            float ang = -7.669903939428206e-4f * (float)t;  // -pi/4096 * t
            float sn, cs; __sincosf(ang, &sn, &cs);
            cplx wku = cplx{cs, sn};
            const float WCc[7] = {1.f, 0.9807852804032304f, 0.9238795325112867f,
                                  0.8314696123025452f, 0.7071067811865476f,
                                  0.5555702330196022f, 0.3826834323650898f};
            const float WCs[7] = {0.f, -0.19509032201612825f, -0.3826834323650898f,
                                  -0.5555702330196022f, -0.7071067811865476f,
                                  -0.8314696123025452f, -0.9238795325112867f};
            const int pc = ((256 - t) & 255) << 4;
            const int pl = (16 - tl) & 15;
#pragma unroll
            for (int m = 1; m <= 6; ++m) {
                const int k = t + (m << 8);
                const int za = t ? (pc | ((15 - m) ^ pl)) : (16 - m);
                cplx Zk = a[T16(m)];
                cplx Zn = Z[za];
                cplx wk = cmul(wku, cplx{WCc[m], WCs[m]});
                cplx Znc = cplx{Zn.x, -Zn.y};
                cplx s  = Zk + Znc;
                cplx dd = Zk - Znc;
                cplx tt = cmul(wk, dd);
                cplx X  = s + cplx{tt.y, -tt.x};   // 2*X[k]
                float P = (X.x * X.x + X.y * X.y) * (1.0f / 32768.0f);
                if ((unsigned)(k - 273) <= 1433u) band += P;   // k in [273,1706]
            }
        }

        // ======== caps: threads 0..5 -> bins {r-1,r,r+1,2r-1,2r,2r+1} ========
        float capP = 0.f;
        if (t < 6) {
            const int c = (t < 3) ? (r - 1 + t) : (2 * r - 4 + t);
            const int kk = (c <= 2048) ? c : (4096 - c);
            const int nb = (4096 - kk) & 4095;
            const int zka = ((kk & 255) << 4) | ((kk >> 8) ^ (kk & 15));
            const int zna = ((nb & 255) << 4) | ((nb >> 8) ^ (nb & 15));
            cplx Zk = Z[zka], Zn = Z[zna];
            float ang = -7.669903939428206e-4f * (float)kk;  // -pi/4096 * kk
            float sn, cs; __sincosf(ang, &sn, &cs);
            cplx wk = cplx{cs, sn};
            cplx Znc = cplx{Zn.x, -Zn.y};
            cplx s  = Zk + Znc;
            cplx dd = Zk - Znc;
            cplx tt = cmul(wk, dd);
            cplx X  = (c <= 2048) ? (s + cplx{tt.y, -tt.x})    // 2*X[kk]
                                  : (s + cplx{-tt.y, tt.x});   // 2*conj(X[4096-kk])
            capP = (X.x * X.x + X.y * X.y) * (1.0f / 32768.0f);
        }
        __syncthreads();   // ALL Z reads (split + caps) done -> zf overlay safe

        if (t < 6) zf[t] = capP;

        // ---- block reduce band ----
#pragma unroll
        for (int off = 32; off > 0; off >>= 1) band += __shfl_down(band, off);
        if ((t & 63) == 0) zf[8 + (t >> 6)] = band;
        __syncthreads();

        if (t == 0) {
            float bb = zf[8] + zf[9] + zf[10] + zf[11];
            float S = zf[1] + zf[4] + 0.5f * (zf[0] + zf[2]);
            float noise = bb;
            const int r2 = 2 * r;
            if (r <= 1706)      noise -= zf[1];
            if (r - 1 >= 273)   noise -= 0.5f * zf[0];
            if (r + 1 <= 1706)  noise -= 0.5f * zf[2];
            if (r2 - 1 <= 1706) noise -= zf[3];
            if (r2 <= 1706)     noise -= zf[4];
            if (r2 + 1 <= 1706) noise -= zf[5];
            lossSum += -10.0f * log10f(S / (noise + 1.0f));
        }

        // ---- rotate pipeline (renamed away by full unroll) ----
        if (it + 1 < ROWS) {
#pragma unroll
            for (int l = 0; l < 16; ++l) a[l] = pf[l];
        }
    }

    if (t == 0) atomicAdd(out, lossSum * (1.0f / 4096.0f));
}

extern "C" void kernel_launch(void* const* d_in, const int* in_sizes, int n_in,
                              void* d_out, int out_size, void* d_ws, size_t ws_size,
                              hipStream_t stream) {
    const float* x = (const float*)d_in[0];    // outputs: (4096, 8192) fp32
    const float* tg = (const float*)d_in[1];   // targets: (4096, 1) fp32
    float* out = (float*)d_out;                // scalar fp32
    hipMemsetAsync(out, 0, sizeof(float), stream);
    snr_kernel<<<4096 / ROWS, TPB, 0, stream>>>(x, tg, out);
}

// Round 5
// 198.565 us; speedup vs baseline: 1.4540x; 1.0300x over previous
//
#include <hip/hip_runtime.h>
#include <math.h>

#define TPB 256
#define ROWS 4   // grid 1024; 2 blocks/CU resident (64 KB LDS each)

// Packed complex: clang ext_vector_type(2) float -> VOP3P v_pk_{add,mul,fma}_f32
typedef float cplx __attribute__((ext_vector_type(2)));

typedef const __attribute__((address_space(1))) char gchar_t;  // global
typedef __attribute__((address_space(3))) char lchar_t;        // LDS

__device__ __forceinline__ cplx cmul(cplx a, cplx b) {
    return a.xx * b + cplx{-a.y, a.y} * b.yx;
}

__device__ __forceinline__ void dft4(cplx& a, cplx& b, cplx& c, cplx& d) {
    cplx t0 = a + c, t1 = a - c, t2 = b + d, t3 = b - d;
    a = t0 + t2;
    c = t0 - t2;
    cplx jt3 = cplx{t3.y, -t3.x};   // -i * t3
    b = t1 + jt3;
    d = t1 - jt3;
}

// In-register 16-point DFT. Input v[l]; output y[m] lands at v[T16(m)].
#define T16(j) (4 * ((j) & 3) + ((j) >> 2))

__device__ __forceinline__ void dft16(cplx v[16]) {
#pragma unroll
    for (int j = 0; j < 4; ++j) dft4(v[j], v[4 + j], v[8 + j], v[12 + j]);
    const float C1 = 0.9238795325112867f, S1 = 0.3826834323650898f;
    const float R2 = 0.7071067811865476f;
    v[5]  = cmul(v[5],  cplx{ C1, -S1});
    v[9]  = cmul(v[9],  cplx{ R2, -R2});
    v[13] = cmul(v[13], cplx{ S1, -C1});
    v[6]  = cmul(v[6],  cplx{ R2, -R2});
    v[10] = cplx{v[10].y, -v[10].x};
    v[14] = cmul(v[14], cplx{-R2, -R2});
    v[7]  = cmul(v[7],  cplx{ S1, -C1});
    v[11] = cmul(v[11], cplx{-R2, -R2});
    v[15] = cmul(v[15], cplx{-C1,  S1});
#pragma unroll
    for (int b = 0; b < 4; ++b) dft4(v[4 * b], v[4 * b + 1], v[4 * b + 2], v[4 * b + 3]);
}

// LDS-only barrier: orders ds ops WITHOUT draining vmcnt, so the next-row
// global_load_lds DMA stays in flight across the FFT's internal exchanges.
// (__syncthreads emits "s_waitcnt vmcnt(0) lgkmcnt(0)" before s_barrier --
// that drain is exactly what serialized every previous version's loads.)
// The "memory" clobbers pin LDS ops on both sides of the s_barrier.
__device__ __forceinline__ void bar_lds() {
    asm volatile("s_waitcnt lgkmcnt(0)" ::: "memory");
    __builtin_amdgcn_s_barrier();
    asm volatile("" ::: "memory");
}

// DMA one 32 KB row into LDS staging: 8 calls/thread, 16 B/lane each.
// LDS dest is wave-uniform base + lane*16 (HW rule); global src is per-lane.
// Zero VGPR cost -> the scheduler cannot sink it toward its use (R4 failure).
__device__ __forceinline__ void dma_row(const float* rowp, char* ldsbase,
                                        int wid, int lane) {
    const char* g = (const char*)rowp + wid * 8192 + lane * 16;
    char* l = ldsbase + wid * 8192;
#pragma unroll
    for (int j = 0; j < 8; ++j) {
        __builtin_amdgcn_global_load_lds((gchar_t*)(g + j * 1024),
                                         (lchar_t*)(l + j * 1024), 16, 0, 0);
    }
}

__global__ __launch_bounds__(TPB, 2) void snr_kernel(const float* __restrict__ x,
                                                     const float* __restrict__ targets,
                                                     float* __restrict__ out) {
    __shared__ __align__(16) cplx A[4096];   // 32 KB staging (linear row image)
    __shared__ __align__(16) cplx B[4096];   // 32 KB exchange + spectrum
    float* zf = (float*)B;                   // overlay: caps [0..5], red [8..11]

    const int t = threadIdx.x;
    const int tl = t & 15;
    const int rb = t ^ ((t >> 4) & 15);   // phys base for logical slots t+256l
    const int wbase = t << 4;
    const int row0 = blockIdx.x * ROWS;
    const int wid = t >> 6, lane = t & 63;

    // ---- hoisted twiddles: depend only on t, invariant across rows ----
    // LDS caps occupancy at 2 blocks/CU, so VGPRs up to 256 are free.
    cplx tw0[16], tw1[16], wkb[7];
    {
        float ang = -1.5339807878856412e-3f * (float)t;  // -2pi/4096 * t
        float sn, cs; __sincosf(ang, &sn, &cs);
        cplx w1 = cplx{cs, sn};
        cplx u2 = cmul(w1, w1), u3 = cmul(u2, w1);
        cplx v4 = cmul(u2, u2), v8 = cmul(v4, v4), v12 = cmul(v8, v4);
        cplx ua[4] = {cplx{1.f, 0.f}, w1, u2, u3};
        cplx vb[4] = {cplx{1.f, 0.f}, v4, v8, v12};
#pragma unroll
        for (int m = 0; m < 16; ++m) tw0[m] = cmul(vb[m >> 2], ua[m & 3]);
    }
    {
        float ang = -0.02454369260617026f * (float)(t >> 4);  // -2pi/256 * p
        float sn, cs; __sincosf(ang, &sn, &cs);
        cplx w1 = cplx{cs, sn};
        cplx u2 = cmul(w1, w1), u3 = cmul(u2, w1);
        cplx v4 = cmul(u2, u2), v8 = cmul(v4, v4), v12 = cmul(v8, v4);
        cplx ua[4] = {cplx{1.f, 0.f}, w1, u2, u3};
        cplx vb[4] = {cplx{1.f, 0.f}, v4, v8, v12};
#pragma unroll
        for (int m = 0; m < 16; ++m) tw1[m] = cmul(vb[m >> 2], ua[m & 3]);
    }
    {
        float ang = -7.669903939428206e-4f * (float)t;  // -pi/4096 * t
        float sn, cs; __sincosf(ang, &sn, &cs);
        cplx wku = cplx{cs, sn};
        const float WCc[7] = {1.f, 0.9807852804032304f, 0.9238795325112867f,
                              0.8314696123025452f, 0.7071067811865476f,
                              0.5555702330196022f, 0.3826834323650898f};
        const float WCs[7] = {0.f, -0.19509032201612825f, -0.3826834323650898f,
                              -0.5555702330196022f, -0.7071067811865476f,
                              -0.8314696123025452f, -0.9238795325112867f};
#pragma unroll
        for (int m = 1; m <= 6; ++m) wkb[m] = cmul(wku, cplx{WCc[m], WCs[m]});
    }

    // ---- prologue: DMA row0 into A; full drain ----
    dma_row(x + (size_t)row0 * 8192, (char*)A, wid, lane);
    __syncthreads();   // vmcnt(0) drain: A = row0

    float lossSum = 0.f;

#pragma unroll 1
    for (int it = 0; it < ROWS; ++it) {
        // ---- regs <- A (linear image; minimal-conflict b64 reads) ----
        cplx a[16];
#pragma unroll
        for (int l = 0; l < 16; ++l) a[l] = A[t + 256 * l];

        // ---- r (uniform per row) ----
        int r;
        {
            float tg = targets[row0 + it];
            const float df = 0.00244140625f;  // 10/4096 exact
            int c0 = (int)(tg * 409.6f) - 2;
            if (c0 < 0) c0 = 0;
            r = c0;
            float best = fabsf(df * (float)c0 - tg);
            for (int i = c0 + 1; i <= c0 + 4 && i <= 4096; ++i) {
                float dd = fabsf(df * (float)i - tg);
                if (dd < best) { best = dd; r = i; }  // strict <: argmin ties
            }
        }

        // ======== stage 0: dest g = 16t + m ========
        dft16(a);
#pragma unroll
        for (int m = 1; m < 16; ++m) { int j = T16(m); a[j] = cmul(a[j], tw0[m]); }
#pragma unroll
        for (int j = 0; j < 16; ++j) B[wbase + (T16(j) ^ tl)] = a[j];
        bar_lds();   // (1) also orders all A-reads chip-wide -> A is free

        // ---- issue next-row DMA into A; drains only at row-end sync ----
        if (it + 1 < ROWS) dma_row(x + (size_t)(row0 + it + 1) * 8192, (char*)A, wid, lane);

        // ======== stage 1 ========
#pragma unroll
        for (int l = 0; l < 16; ++l) a[l] = B[rb + (l << 8)];
        bar_lds();   // (2) in-place exchange: reads before writes
        dft16(a);
#pragma unroll
        for (int m = 1; m < 16; ++m) { int j = T16(m); a[j] = cmul(a[j], tw1[m]); }
        {
            const int base1 = (t >> 4) << 8;
#pragma unroll
            for (int m = 0; m < 16; ++m) B[base1 + (m << 4) + (tl ^ m)] = a[T16(m)];
        }
        bar_lds();   // (3)

        // ======== stage 2 (twiddle-free) ========
#pragma unroll
        for (int l = 0; l < 16; ++l) a[l] = B[rb + (l << 8)];
        bar_lds();   // (4)
        dft16(a);
        // a[T16(m)] = Z4096 bin (t + 256m)

        // ======== export spectrum: bin t+256m -> logical slot 16t+m ========
#pragma unroll
        for (int j = 0; j < 16; ++j) B[wbase + (T16(j) ^ tl)] = a[j];
        bar_lds();   // (5)

        // ======== band sum: bins [273,1706] == {t+256m : m in [1,6]} ========
        float band = 0.f;
        {
            const int pc = ((256 - t) & 255) << 4;
            const int pl = (16 - tl) & 15;
#pragma unroll
            for (int m = 1; m <= 6; ++m) {
                const int k = t + (m << 8);
                const int za = t ? (pc | ((15 - m) ^ pl)) : (16 - m);
                cplx Zk = a[T16(m)];
                cplx Zn = B[za];
                cplx Znc = cplx{Zn.x, -Zn.y};
                cplx s  = Zk + Znc;
                cplx dd = Zk - Znc;
                cplx tt = cmul(wkb[m], dd);
                cplx X  = s + cplx{tt.y, -tt.x};   // 2*X[k]
                float P = (X.x * X.x + X.y * X.y) * (1.0f / 32768.0f);
                if ((unsigned)(k - 273) <= 1433u) band += P;
            }
        }

        // ======== caps: threads 0..5 -> bins {r-1,r,r+1,2r-1,2r,2r+1} ========
        float capP = 0.f;
        if (t < 6) {
            const int c = (t < 3) ? (r - 1 + t) : (2 * r - 4 + t);
            const int kk = (c <= 2048) ? c : (4096 - c);
            const int nb = (4096 - kk) & 4095;
            const int zka = ((kk & 255) << 4) | ((kk >> 8) ^ (kk & 15));
            const int zna = ((nb & 255) << 4) | ((nb >> 8) ^ (nb & 15));
            cplx Zk = B[zka], Zn = B[zna];
            float ang = -7.669903939428206e-4f * (float)kk;
            float sn, cs; __sincosf(ang, &sn, &cs);
            cplx wk = cplx{cs, sn};
            cplx Znc = cplx{Zn.x, -Zn.y};
            cplx s  = Zk + Znc;
            cplx dd = Zk - Znc;
            cplx tt = cmul(wk, dd);
            cplx X  = (c <= 2048) ? (s + cplx{tt.y, -tt.x})
                                  : (s + cplx{-tt.y, tt.x});
            capP = (X.x * X.x + X.y * X.y) * (1.0f / 32768.0f);
        }
        bar_lds();   // (6) all B reads done -> zf overlay safe

        if (t < 6) zf[t] = capP;

#pragma unroll
        for (int off = 32; off > 0; off >>= 1) band += __shfl_down(band, off);
        if ((t & 63) == 0) zf[8 + (t >> 6)] = band;

        // (7) FULL sync: drains vmcnt -> next-row DMA into A is complete,
        // and zf writes are visible for the epilogue.
        __syncthreads();

        if (t == 0) {
            float bb = zf[8] + zf[9] + zf[10] + zf[11];
            float S = zf[1] + zf[4] + 0.5f * (zf[0] + zf[2]);
            float noise = bb;
            const int r2 = 2 * r;
            if (r <= 1706)      noise -= zf[1];
            if (r - 1 >= 273)   noise -= 0.5f * zf[0];
            if (r + 1 <= 1706)  noise -= 0.5f * zf[2];
            if (r2 - 1 <= 1706) noise -= zf[3];
            if (r2 <= 1706)     noise -= zf[4];
            if (r2 + 1 <= 1706) noise -= zf[5];
            lossSum += -10.0f * log10f(S / (noise + 1.0f));
        }
    }

    if (t == 0) atomicAdd(out, lossSum * (1.0f / 4096.0f));
}

extern "C" void kernel_launch(void* const* d_in, const int* in_sizes, int n_in,
                              void* d_out, int out_size, void* d_ws, size_t ws_size,
                              hipStream_t stream) {
    const float* x = (const float*)d_in[0];    // outputs: (4096, 8192) fp32
    const float* tg = (const float*)d_in[1];   // targets: (4096, 1) fp32
    float* out = (float*)d_out;                // scalar fp32
    hipMemsetAsync(out, 0, sizeof(float), stream);
    snr_kernel<<<4096 / ROWS, TPB, 0, stream>>>(x, tg, out);
}